// Round 7
// baseline (977.477 us; speedup 1.0000x reference)
//
#include <hip/hip_runtime.h>

// Problem constants (fixed by the reference file).
#define GHN 800000
#define GCN 20000
#define GSN 65000
#define GT  885000          // total groups
#define TSTEPS 10

// Fixed-point group-sum encoding, one uint64 per group:
//   bits [0,51)  : sum of round(transm * 2^44)
//   bits [51,64) : member count
#define FIXD   17592186044416.0          // 2^44
#define INVFIX (1.0 / 17592186044416.0)  // 2^-44
#define DELTA  3518437208883ULL          // round(0.2 * 2^44)
#define CUNIT  (1ULL << 51)
#define SMASK  (CUNIT - 1ULL)

#define APT 8               // agents per thread; one live-mask byte per thread

typedef float vf4 __attribute__((ext_vector_type(4)));

// ---------------------------------------------------------------------------
// init: 8 agents/thread. Scatters (count | fixed-point transm) u64 atomics for
// ALL agents (reference segment-sums over everyone), and packs the live mask
// (susc != 0) into one byte per thread. Atomic count unchanged (6M) -- this
// kernel sits at the measured ~22.8 G atomics/s ceiling (263 us, R2/R6).
// ---------------------------------------------------------------------------
__global__ void init_kernel(const float* __restrict__ transm_in,
                            const float* __restrict__ susc_in,
                            const int* __restrict__ gh,
                            const int* __restrict__ gc,
                            const int* __restrict__ gs,
                            unsigned long long* __restrict__ buf,
                            unsigned char* __restrict__ live,
                            int n) {
    int tid = blockIdx.x * blockDim.x + threadIdx.x;
    int base = tid * APT;
    if (base >= n) return;            // n % 8 == 0: full octet per thread

    float tr[APT], su[APT];
    int ga[APT], gb[APT], gcx[APT];
    *(float4*)&tr[0] = *(const float4*)(transm_in + base);
    *(float4*)&tr[4] = *(const float4*)(transm_in + base + 4);
    *(float4*)&su[0] = *(const float4*)(susc_in + base);
    *(float4*)&su[4] = *(const float4*)(susc_in + base + 4);
    *(int4*)&ga[0]  = *(const int4*)(gh + base);
    *(int4*)&ga[4]  = *(const int4*)(gh + base + 4);
    *(int4*)&gb[0]  = *(const int4*)(gc + base);
    *(int4*)&gb[4]  = *(const int4*)(gc + base + 4);
    *(int4*)&gcx[0] = *(const int4*)(gs + base);
    *(int4*)&gcx[4] = *(const int4*)(gs + base + 4);

    unsigned int m = 0;
#pragma unroll
    for (int j = 0; j < APT; ++j)
        m |= (su[j] != 0.0f ? 1u : 0u) << j;
    live[tid] = (unsigned char)m;

#pragma unroll
    for (int j = 0; j < APT; ++j) {
        unsigned long long e =
            (unsigned long long)((double)tr[j] * FIXD + 0.5) + CUNIT;
        atomicAdd(&buf[ga[j]], e);
        atomicAdd(&buf[GHN + gb[j]], e);
        atomicAdd(&buf[GHN + GCN + gcx[j]], e);
    }
}

// ---------------------------------------------------------------------------
// combine: 4 groups/thread, plain vector loads/stores (kernel-boundary
// coherence). cur[g] = (beta*p_contact)*segsum; expression tree identical to
// rounds 2/4/5/6 (absmax 0). Edge-type boundaries 800000/820000 are %4==0.
// ---------------------------------------------------------------------------
__global__ void combine_kernel(const float* __restrict__ betas,
                               const unsigned long long* __restrict__ buf,
                               float* __restrict__ cur) {
    int g4 = (blockIdx.x * blockDim.x + threadIdx.x) * 4;
    if (g4 >= GT) return;
    ulonglong2 v01 = *(const ulonglong2*)(buf + g4);
    ulonglong2 v23 = *(const ulonglong2*)(buf + g4 + 2);
    float beta = (g4 < GHN) ? betas[0] : (g4 < GHN + GCN) ? betas[1] : betas[2];
    unsigned long long vv[4] = {v01.x, v01.y, v23.x, v23.y};
    vf4 o;
#pragma unroll
    for (int k = 0; k < 4; ++k) {
        unsigned long long v = vv[k];
        float people = (float)(v >> 51);
        float p = fminf(1.0f / (people - 1.0f), 1.0f);  // count==1 -> inf -> 1
        float sum = (float)((double)(long long)(v & SMASK) * INVFIX);
        o[k] = (beta * p) * sum;
    }
    *(vf4*)(cur + g4) = o;
}

// ---------------------------------------------------------------------------
// step: 8 agents/thread, live mask in one ws byte per thread (no float susc
// traffic). All-dead threads skip gid/gumbel loads and gathers entirely and
// just write zeros. Decision math byte-identical to R2/R6 (absmax 0).
// Infected agents clear their mask bit and scatter the exact +0.2 fixed-point
// delta for the next step's combine. Already-infected agents cannot be
// re-infected (needs g1-g0 > 34.5; pre-sampled gumbel diff caps at ~19.6).
// ---------------------------------------------------------------------------
template <bool LAST>
__global__ void step_kernel(const float* __restrict__ gum_t,  // gumbel + 2*t*n
                            const int* __restrict__ gh,
                            const int* __restrict__ gc,
                            const int* __restrict__ gs,
                            const float* __restrict__ cur,
                            unsigned long long* __restrict__ buf,
                            unsigned char* __restrict__ live,
                            float* __restrict__ out_t,        // out + t*n
                            int n) {
    int tid = blockIdx.x * blockDim.x + threadIdx.x;
    int base = tid * APT;
    if (base >= n) return;

    vf4 zero = {0.0f, 0.0f, 0.0f, 0.0f};
    unsigned int m = live[tid];
    if (m == 0) {                     // whole octet dead: zeros only
        __builtin_nontemporal_store(zero, (vf4*)(out_t + base));
        __builtin_nontemporal_store(zero, (vf4*)(out_t + base + 4));
        return;
    }

    int ga[APT], gb[APT], gcx[APT];
    *(int4*)&ga[0]  = *(const int4*)(gh + base);
    *(int4*)&ga[4]  = *(const int4*)(gh + base + 4);
    *(int4*)&gb[0]  = *(const int4*)(gc + base);
    *(int4*)&gb[4]  = *(const int4*)(gc + base + 4);
    *(int4*)&gcx[0] = *(const int4*)(gs + base);
    *(int4*)&gcx[4] = *(const int4*)(gs + base + 4);
#pragma unroll
    for (int j = 0; j < APT; ++j) {
        gb[j]  += GHN;
        gcx[j] += GHN + GCN;
    }

    float g0a[APT], g1a[APT];
    *(vf4*)&g0a[0] = __builtin_nontemporal_load((const vf4*)(gum_t + base));
    *(vf4*)&g0a[4] = __builtin_nontemporal_load((const vf4*)(gum_t + base + 4));
    *(vf4*)&g1a[0] = __builtin_nontemporal_load((const vf4*)(gum_t + n + base));
    *(vf4*)&g1a[4] = __builtin_nontemporal_load((const vf4*)(gum_t + n + base + 4));

    // Unconditional parallel gathers (indices always valid): max MLP.
    float ca[APT], cb[APT], cc[APT];
#pragma unroll
    for (int j = 0; j < APT; ++j) {
        ca[j] = cur[ga[j]];
        cb[j] = cur[gb[j]];
        cc[j] = cur[gcx[j]];
    }

    float og[APT];
#pragma unroll
    for (int j = 0; j < APT; ++j) og[j] = 0.0f;

    const unsigned int m0 = m;
#pragma unroll
    for (int j = 0; j < APT; ++j) {
        if (m & (1u << j)) {
            // reference add order: household, company, school (s==1 exactly)
            float ts = ca[j];
            ts += cb[j];
            ts += cc[j];
            float ni = expf(-ts);                    // not_infected
            float l0 = logf(fmaxf(ni, 1e-15f));
            float l1 = logf(fmaxf(1.0f - ni, 1e-15f));
            float z0 = (l0 + g0a[j]) / 0.1f;         // TAU = 0.1
            float z1 = (l1 + g1a[j]) / 0.1f;
            if (z1 > z0) {                           // argmax tie -> class 0
                og[j] = 1.0f;
                m &= ~(1u << j);
                if (!LAST) {
                    atomicAdd(&buf[ga[j]],  DELTA);
                    atomicAdd(&buf[gb[j]],  DELTA);
                    atomicAdd(&buf[gcx[j]], DELTA);
                }
            }
        }
    }

    if (m != m0) live[tid] = (unsigned char)m;
    __builtin_nontemporal_store(*(vf4*)&og[0], (vf4*)(out_t + base));
    __builtin_nontemporal_store(*(vf4*)&og[4], (vf4*)(out_t + base + 4));
}

extern "C" void kernel_launch(void* const* d_in, const int* in_sizes, int n_in,
                              void* d_out, int out_size, void* d_ws, size_t ws_size,
                              hipStream_t stream) {
    const float* betas     = (const float*)d_in[0];
    const float* transm_in = (const float*)d_in[1];
    const float* susc_in   = (const float*)d_in[2];
    const float* gumbel    = (const float*)d_in[3];
    const int*   gh        = (const int*)d_in[4];
    const int*   gc        = (const int*)d_in[5];
    const int*   gs        = (const int*)d_in[6];
    const int    n         = in_sizes[1];         // 2,000,000
    float*       out       = (float*)d_out;

    // Workspace layout: GT u64 (buf) + GT f32 (cur) + n/8 bytes (live mask)
    // = 10.62 MB + 250 KB.
    unsigned long long* buf = (unsigned long long*)d_ws;
    float* cur = (float*)((char*)d_ws + (size_t)GT * 8);
    unsigned char* live = (unsigned char*)((char*)d_ws + (size_t)GT * 12);

    const int blk = 256;
    const int grid_oct  = (n / APT + blk - 1) / blk;        // 977
    const int grid_comb = (GT / 4 + blk - 1) / blk;         // 865

    hipMemsetAsync(buf, 0, (size_t)GT * 8, stream);

    init_kernel<<<grid_oct, blk, 0, stream>>>(transm_in, susc_in,
                                              gh, gc, gs, buf, live, n);

    for (int t = 0; t < TSTEPS; ++t) {
        const float* gum_t = gumbel + (size_t)2 * t * n;
        float* out_t = out + (size_t)t * n;

        combine_kernel<<<grid_comb, blk, 0, stream>>>(betas, buf, cur);

        if (t == TSTEPS - 1) {
            step_kernel<true><<<grid_oct, blk, 0, stream>>>(
                gum_t, gh, gc, gs, cur, buf, live, out_t, n);
        } else {
            step_kernel<false><<<grid_oct, blk, 0, stream>>>(
                gum_t, gh, gc, gs, cur, buf, live, out_t, n);
        }
    }
}